// Round 5
// baseline (555.889 us; speedup 1.0000x reference)
//
#include <hip/hip_runtime.h>
#include <hip/hip_bf16.h>

// LexionAdapter — fp32 I/O (per reference dtypes), bf16-MFMA compute.
//   Wc[f,d] = sum_e attn_W[f,e] Ww[e,d]        (NN, 768^3)        -> d_ws
//   R[bl,d] = sum_f LO[bl,f] Wc[f,d]           (NN)               -> d_out
//   x1_attn: per 64 WE rows (8 bl): X1 = tanh(WE.Wt^T + bt) bf16 in LDS;
//            logit[w] = X1[w].R[bl]  (q.bw term is w-constant -> cancels);
//            alpha = softmax; Y = sum_w alpha_w X1[w] -> d_out (elementwise
//            over R, same thread reads/writes -> race-free).
//   y_ww_ln: C = Y.Ww^T + bw + LO (64 rows, LDS); LayerNorm -> d_out in-place
//            (each 64-row range touched by exactly one block).
// Equivalent to reference: softmax shift-invariance + sum(alpha)=1.

typedef __bf16 bf16_t;
typedef bf16_t bf16x4 __attribute__((ext_vector_type(4)));
typedef bf16_t bf16x8 __attribute__((ext_vector_type(8)));
typedef float f32x4 __attribute__((ext_vector_type(4)));

__device__ __forceinline__ bf16x4 cvt4(float4 v) {
  bf16x4 o;
  o[0] = (bf16_t)v.x; o[1] = (bf16_t)v.y;
  o[2] = (bf16_t)v.z; o[3] = (bf16_t)v.w;
  return o;
}

// ---------------------------------------------------------------------------
// NN GEMM: C[M,N] = A[M,K].B[K,N], fp32 row-major, K = 32*kFull.
// 128x128 tile; fp32 loads -> bf16 LDS; 16x16x32 bf16 MFMA.
// ---------------------------------------------------------------------------
__global__ __launch_bounds__(256, 2) void gemm_nn(
    const float* __restrict__ A, const float* __restrict__ B,
    float* __restrict__ C, int ldA, int ldB, int N_out, int kFull) {
  __shared__ __align__(16) bf16_t As[128 * 32];  // [m][k]
  __shared__ __align__(16) bf16_t Bs[32 * 128];  // [k][n]

  const int t = threadIdx.x;
  const int lane = t & 63, wave = t >> 6;
  const int wr = wave >> 1, wc = wave & 1;
  const int quad = lane >> 4, l16 = lane & 15;
  const long m0 = (long)blockIdx.y * 128;
  const long n0 = (long)blockIdx.x * 128;

  f32x4 acc[4][4] = {};

  for (int kt = 0; kt < kFull; ++kt) {
    const int k0 = kt * 32;
#pragma unroll
    for (int r = 0; r < 4; ++r) {
      const int f = r * 256 + t;
      // A: 128 rows x 32 fp32 = 1024 float4
      const int arow = f >> 3, ak = (f & 7) * 4;
      float4 va = *(const float4*)(A + (m0 + arow) * ldA + k0 + ak);
      *(bf16x4*)&As[arow * 32 + ak] = cvt4(va);
      // B: 32 rows x 128 fp32 = 1024 float4
      const int brow = f >> 5, bc = (f & 31) * 4;
      float4 vb = *(const float4*)(B + (long)(k0 + brow) * ldB + n0 + bc);
      *(bf16x4*)&Bs[brow * 128 + bc] = cvt4(vb);
    }
    __syncthreads();

    bf16x8 af[4], bfv[4];
#pragma unroll
    for (int i = 0; i < 4; ++i)
      af[i] = *(const bf16x8*)&As[(wr * 64 + i * 16 + l16) * 32 + quad * 8];
#pragma unroll
    for (int j = 0; j < 4; ++j) {
      const int n = wc * 64 + j * 16 + l16;
#pragma unroll
      for (int jj = 0; jj < 8; ++jj)
        bfv[j][jj] = Bs[(quad * 8 + jj) * 128 + n];
    }
#pragma unroll
    for (int i = 0; i < 4; ++i)
#pragma unroll
      for (int j = 0; j < 4; ++j)
        acc[i][j] = __builtin_amdgcn_mfma_f32_16x16x32_bf16(af[i], bfv[j],
                                                            acc[i][j], 0, 0, 0);
    __syncthreads();
  }

  // C/D layout: col = lane&15, row = (lane>>4)*4 + reg  [m89/m91]
#pragma unroll
  for (int j = 0; j < 4; ++j) {
    const long n = n0 + wc * 64 + j * 16 + l16;
#pragma unroll
    for (int i = 0; i < 4; ++i) {
      const long mBase = m0 + wr * 64 + i * 16 + quad * 4;
#pragma unroll
      for (int r = 0; r < 4; ++r)
        C[(mBase + r) * N_out + n] = acc[i][j][r];
    }
  }
}

// ---------------------------------------------------------------------------
// Fused X1 + attention. One block = 64 WE rows = 8 (b,l). NT vs Wt, K=200.
// ---------------------------------------------------------------------------
__global__ __launch_bounds__(256, 1) void x1_attn(
    const float* __restrict__ WE,   // [65536, 200]
    const float* __restrict__ Wt,   // [768, 200]
    const float* __restrict__ bt,   // [768]
    float* __restrict__ RY) {       // [8192, 768] in: R, out: Y
  __shared__ __align__(16) bf16_t X1buf[64 * 768];  // 96 KiB
  __shared__ __align__(16) bf16_t As[64 * 32];      // 4 KiB  [m][k]
  __shared__ __align__(16) bf16_t Bs[128 * 32];     // 8 KiB  [n][k]
  __shared__ float red[8][4];

  const int t = threadIdx.x;
  const int lane = t & 63, wave = t >> 6;
  const int quad = lane >> 4, l16 = lane & 15;
  const long m0 = (long)blockIdx.x * 64;
  const bf16x4 z4 = {(bf16_t)0.f, (bf16_t)0.f, (bf16_t)0.f, (bf16_t)0.f};

  // ---- Phase A: X1[64,768] = tanh(WE.Wt^T + bt) -> LDS (bf16) ----
  for (int nt = 0; nt < 6; ++nt) {
    f32x4 acc[8] = {};
    for (int kt = 0; kt < 6; ++kt) {
      const int k0 = kt * 32;
#pragma unroll
      for (int r = 0; r < 2; ++r) {  // As: 64x32 = 512 float4
        const int f = r * 256 + t;
        const int arow = f >> 3, ak = (f & 7) * 4;
        float4 va = *(const float4*)(WE + (m0 + arow) * 200 + k0 + ak);
        *(bf16x4*)&As[arow * 32 + ak] = cvt4(va);
      }
#pragma unroll
      for (int r = 0; r < 4; ++r) {  // Bs: 128x32 = 1024 float4
        const int f = r * 256 + t;
        const int brow = f >> 3, bk = (f & 7) * 4;
        float4 vb = *(const float4*)(Wt + (long)(nt * 128 + brow) * 200 + k0 + bk);
        *(bf16x4*)&Bs[brow * 32 + bk] = cvt4(vb);
      }
      __syncthreads();
      const bf16x8 af = *(const bf16x8*)&As[(wave * 16 + l16) * 32 + quad * 8];
#pragma unroll
      for (int j = 0; j < 8; ++j) {
        const bf16x8 bfr = *(const bf16x8*)&Bs[(j * 16 + l16) * 32 + quad * 8];
        acc[j] = __builtin_amdgcn_mfma_f32_16x16x32_bf16(af, bfr, acc[j], 0, 0, 0);
      }
      __syncthreads();
    }
    {  // k-tail: 8 fp32 at element offset 192 of each 200-row; zero-pad to 32
      const int rowA = t >> 2, qa = t & 3;
      if (qa == 0) {
        float4 v0 = *(const float4*)(WE + (m0 + rowA) * 200 + 192);
        float4 v1 = *(const float4*)(WE + (m0 + rowA) * 200 + 196);
        *(bf16x4*)&As[rowA * 32 + 0] = cvt4(v0);
        *(bf16x4*)&As[rowA * 32 + 4] = cvt4(v1);
      } else {
        *(bf16x4*)&As[rowA * 32 + qa * 8] = z4;
        *(bf16x4*)&As[rowA * 32 + qa * 8 + 4] = z4;
      }
#pragma unroll
      for (int r = 0; r < 2; ++r) {
        const int idx = r * 256 + t;
        const int rowB = idx >> 2, qb = idx & 3;
        if (qb == 0) {
          float4 v0 = *(const float4*)(Wt + (long)(nt * 128 + rowB) * 200 + 192);
          float4 v1 = *(const float4*)(Wt + (long)(nt * 128 + rowB) * 200 + 196);
          *(bf16x4*)&Bs[rowB * 32 + 0] = cvt4(v0);
          *(bf16x4*)&Bs[rowB * 32 + 4] = cvt4(v1);
        } else {
          *(bf16x4*)&Bs[rowB * 32 + qb * 8] = z4;
          *(bf16x4*)&Bs[rowB * 32 + qb * 8 + 4] = z4;
        }
      }
      __syncthreads();
      const bf16x8 af = *(const bf16x8*)&As[(wave * 16 + l16) * 32 + quad * 8];
#pragma unroll
      for (int j = 0; j < 8; ++j) {
        const bf16x8 bfr = *(const bf16x8*)&Bs[(j * 16 + l16) * 32 + quad * 8];
        acc[j] = __builtin_amdgcn_mfma_f32_16x16x32_bf16(af, bfr, acc[j], 0, 0, 0);
      }
      __syncthreads();
    }
    // epilogue: tanh(acc + bt) -> X1buf  (C/D: col=l16, row=quad*4+reg)
#pragma unroll
    for (int j = 0; j < 8; ++j) {
      const int n = nt * 128 + j * 16 + l16;
      const float bv = bt[n];
#pragma unroll
      for (int r = 0; r < 4; ++r) {
        const int ml = wave * 16 + quad * 4 + r;
        X1buf[ml * 768 + n] = (bf16_t)tanhf(acc[j][r] + bv);
      }
    }
    __syncthreads();
  }

  // ---- Phase B: attention per bl ----
  for (int blc = 0; blc < 8; ++blc) {
    const long bl = (long)blockIdx.x * 8 + blc;
    float rv[3], x1[8][3];
#pragma unroll
    for (int j = 0; j < 3; ++j) {
      const int d = t + j * 256;
      rv[j] = RY[bl * 768 + d];
#pragma unroll
      for (int w = 0; w < 8; ++w)
        x1[w][j] = (float)X1buf[(blc * 8 + w) * 768 + d];
    }
    float part[8];
#pragma unroll
    for (int w = 0; w < 8; ++w)
      part[w] = x1[w][0] * rv[0] + x1[w][1] * rv[1] + x1[w][2] * rv[2];
#pragma unroll
    for (int o = 32; o > 0; o >>= 1)
#pragma unroll
      for (int w = 0; w < 8; ++w) part[w] += __shfl_down(part[w], o, 64);
    if (lane == 0)
#pragma unroll
      for (int w = 0; w < 8; ++w) red[w][wave] = part[w];
    __syncthreads();
    float logit[8], mx = -1e30f;
#pragma unroll
    for (int w = 0; w < 8; ++w) {
      logit[w] = red[w][0] + red[w][1] + red[w][2] + red[w][3];
      mx = fmaxf(mx, logit[w]);
    }
    float aw[8], s = 0.f;
#pragma unroll
    for (int w = 0; w < 8; ++w) {
      aw[w] = __expf(logit[w] - mx);
      s += aw[w];
    }
    const float inv = 1.f / s;
#pragma unroll
    for (int j = 0; j < 3; ++j) {
      float y = 0.f;
#pragma unroll
      for (int w = 0; w < 8; ++w) y += aw[w] * x1[w][j];
      RY[bl * 768 + t + j * 256] = y * inv;  // exactly the elems this thread read
    }
    __syncthreads();
  }
}

// ---------------------------------------------------------------------------
// Fused final GEMM + residual + LayerNorm, in-place on d_out (fp32).
// One block = 64 rows. NT vs Ww (contraction over trailing d).
// ---------------------------------------------------------------------------
__global__ __launch_bounds__(256, 1) void y_ww_ln(
    const float* __restrict__ Y,    // d_out, [8192,768]
    const float* __restrict__ Ww,   // [768,768]
    const float* __restrict__ bw,   // [768]
    const float* __restrict__ LO,   // [8192,768]
    const float* __restrict__ gamma, const float* __restrict__ beta,
    float* __restrict__ out) {      // d_out (in-place)
  __shared__ __align__(16) bf16_t Cbuf[64 * 768];  // 96 KiB
  __shared__ __align__(16) bf16_t As[64 * 32];     // [m][k]
  __shared__ __align__(16) bf16_t Bs[128 * 32];    // [n][k]
  __shared__ float rowstats[64][2];

  const int t = threadIdx.x;
  const int lane = t & 63, wave = t >> 6;
  const int quad = lane >> 4, l16 = lane & 15;
  const long m0 = (long)blockIdx.x * 64;

  float s1[4] = {0.f, 0.f, 0.f, 0.f}, s2[4] = {0.f, 0.f, 0.f, 0.f};

  for (int nt = 0; nt < 6; ++nt) {
    f32x4 acc[8] = {};
    for (int kt = 0; kt < 24; ++kt) {
      const int k0 = kt * 32;
#pragma unroll
      for (int r = 0; r < 2; ++r) {  // As: 64x32
        const int f = r * 256 + t;
        const int arow = f >> 3, ak = (f & 7) * 4;
        float4 va = *(const float4*)(Y + (m0 + arow) * 768 + k0 + ak);
        *(bf16x4*)&As[arow * 32 + ak] = cvt4(va);
      }
#pragma unroll
      for (int r = 0; r < 4; ++r) {  // Bs: 128x32
        const int f = r * 256 + t;
        const int brow = f >> 3, bk = (f & 7) * 4;
        float4 vb = *(const float4*)(Ww + (long)(nt * 128 + brow) * 768 + k0 + bk);
        *(bf16x4*)&Bs[brow * 32 + bk] = cvt4(vb);
      }
      __syncthreads();
      const bf16x8 af = *(const bf16x8*)&As[(wave * 16 + l16) * 32 + quad * 8];
#pragma unroll
      for (int j = 0; j < 8; ++j) {
        const bf16x8 bfr = *(const bf16x8*)&Bs[(j * 16 + l16) * 32 + quad * 8];
        acc[j] = __builtin_amdgcn_mfma_f32_16x16x32_bf16(af, bfr, acc[j], 0, 0, 0);
      }
      __syncthreads();
    }
#pragma unroll
    for (int j = 0; j < 8; ++j) {
      const int n = nt * 128 + j * 16 + l16;
      const float bwv = bw[n];
#pragma unroll
      for (int r = 0; r < 4; ++r) {
        const int ml = wave * 16 + quad * 4 + r;
        const float fv = acc[j][r] + bwv + LO[(m0 + ml) * 768 + n];
        Cbuf[ml * 768 + n] = (bf16_t)fv;
        s1[r] += fv;
        s2[r] += fv * fv;
      }
    }
  }
  // reduce across the 16 lanes sharing each row
#pragma unroll
  for (int o = 8; o > 0; o >>= 1)
#pragma unroll
    for (int r = 0; r < 4; ++r) {
      s1[r] += __shfl_down(s1[r], o, 16);
      s2[r] += __shfl_down(s2[r], o, 16);
    }
  if (l16 == 0)
#pragma unroll
    for (int r = 0; r < 4; ++r) {
      const int ml = wave * 16 + quad * 4 + r;
      rowstats[ml][0] = s1[r];
      rowstats[ml][1] = s2[r];
    }
  __syncthreads();

  float gv[3], bv2[3];
#pragma unroll
  for (int j = 0; j < 3; ++j) {
    gv[j] = gamma[t + j * 256];
    bv2[j] = beta[t + j * 256];
  }
  for (int r64 = 0; r64 < 64; ++r64) {
    const float mu = rowstats[r64][0] * (1.f / 768.f);
    const float var = rowstats[r64][1] * (1.f / 768.f) - mu * mu;
    const float istd = rsqrtf(var + 1e-12f);
#pragma unroll
    for (int j = 0; j < 3; ++j) {
      const int d = t + j * 256;
      const float val = ((float)Cbuf[r64 * 768 + d] - mu) * istd * gv[j] + bv2[j];
      out[(m0 + r64) * 768 + d] = val;
    }
  }
}

// ---------------------------------------------------------------------------
extern "C" void kernel_launch(void* const* d_in, const int* in_sizes, int n_in,
                              void* d_out, int out_size, void* d_ws,
                              size_t ws_size, hipStream_t stream) {
  (void)in_sizes; (void)n_in; (void)out_size; (void)ws_size;
  const float* WE = (const float*)d_in[0];   // [65536, 200]
  const float* LO = (const float*)d_in[1];   // [8192, 768]
  const float* Wt = (const float*)d_in[2];   // [768, 200]
  const float* bt = (const float*)d_in[3];   // [768]
  const float* Ww = (const float*)d_in[4];   // [768, 768]
  const float* bw = (const float*)d_in[5];   // [768]
  const float* aW = (const float*)d_in[6];   // [768, 768]
  const float* g  = (const float*)d_in[7];   // [768]
  const float* bb = (const float*)d_in[8];   // [768]
  float* out = (float*)d_out;                // [8192, 768]

  float* Wc = (float*)d_ws;  // 768*768*4 = 2.36 MB — only scratch used

  const dim3 blk(256);

  // Wc = attn_W . Ww   (NN, 768^3)
  gemm_nn<<<dim3(6, 6), blk, 0, stream>>>(aW, Ww, Wc, 768, 768, 768, 24);
  // R = LO . Wc  -> d_out
  gemm_nn<<<dim3(6, 64), blk, 0, stream>>>(LO, Wc, out, 768, 768, 768, 24);
  // X1 + attention; Y overwrites R elementwise in d_out
  x1_attn<<<dim3(1024), blk, 0, stream>>>(WE, Wt, bt, out);
  // weighted + residual + LayerNorm, in-place on d_out
  y_ww_ln<<<dim3(128), blk, 0, stream>>>(out, Ww, bw, LO, g, bb, out);
}

// Round 6
// 444.556 us; speedup vs baseline: 1.2504x; 1.2504x over previous
//
#include <hip/hip_runtime.h>
#include <hip/hip_bf16.h>

// LexionAdapter — fp32 I/O, bf16-MFMA compute, un-fused latency-optimized.
//   Wc = attn_W . Ww                      (NN)  -> ws
//   R  = LO . Wc                          (NN)  -> d_out
//   X1 = tanh(WE . Wt^T + bt)  bf16       (NT)  -> ws chunk  [m97-class tiles]
//   attn_soft: logit[w] = X1[w].R ; softmax ; Y -> d_out (elementwise over R)
//   y_ww_ln:  out = LN(Y.Ww^T + bw + LO)  in-place, 32 rows/block (256 blocks)
// q.bw logit term is w-constant -> cancels in softmax. sum(alpha)=1 removes
// the bias/residual coupling. Exactly equivalent to the reference.

typedef __bf16 bf16_t;
typedef bf16_t bf16x4 __attribute__((ext_vector_type(4)));
typedef bf16_t bf16x8 __attribute__((ext_vector_type(8)));
typedef float f32x4 __attribute__((ext_vector_type(4)));

__device__ __forceinline__ bf16x4 cvt4(float4 v) {
  bf16x4 o;
  o[0] = (bf16_t)v.x; o[1] = (bf16_t)v.y;
  o[2] = (bf16_t)v.z; o[3] = (bf16_t)v.w;
  return o;
}

// ---------------------------------------------------------------------------
// NN GEMM: C[M,N] = A[M,K].B[K,N], fp32, K = 32*kFull. 128x128 tile.
// ---------------------------------------------------------------------------
__global__ __launch_bounds__(256, 2) void gemm_nn(
    const float* __restrict__ A, const float* __restrict__ B,
    float* __restrict__ C, int ldA, int ldB, int N_out, int kFull) {
  __shared__ __align__(16) bf16_t As[128 * 32];  // [m][k]
  __shared__ __align__(16) bf16_t Bs[32 * 128];  // [k][n]

  const int t = threadIdx.x;
  const int lane = t & 63, wave = t >> 6;
  const int wr = wave >> 1, wc = wave & 1;
  const int quad = lane >> 4, l16 = lane & 15;
  const long m0 = (long)blockIdx.y * 128;
  const long n0 = (long)blockIdx.x * 128;

  f32x4 acc[4][4] = {};

  for (int kt = 0; kt < kFull; ++kt) {
    const int k0 = kt * 32;
#pragma unroll
    for (int r = 0; r < 4; ++r) {
      const int f = r * 256 + t;
      const int arow = f >> 3, ak = (f & 7) * 4;
      float4 va = *(const float4*)(A + (m0 + arow) * ldA + k0 + ak);
      *(bf16x4*)&As[arow * 32 + ak] = cvt4(va);
      const int brow = f >> 5, bc = (f & 31) * 4;
      float4 vb = *(const float4*)(B + (long)(k0 + brow) * ldB + n0 + bc);
      *(bf16x4*)&Bs[brow * 128 + bc] = cvt4(vb);
    }
    __syncthreads();

    bf16x8 af[4], bfv[4];
#pragma unroll
    for (int i = 0; i < 4; ++i)
      af[i] = *(const bf16x8*)&As[(wr * 64 + i * 16 + l16) * 32 + quad * 8];
#pragma unroll
    for (int j = 0; j < 4; ++j) {
      const int n = wc * 64 + j * 16 + l16;
#pragma unroll
      for (int jj = 0; jj < 8; ++jj)
        bfv[j][jj] = Bs[(quad * 8 + jj) * 128 + n];
    }
#pragma unroll
    for (int i = 0; i < 4; ++i)
#pragma unroll
      for (int j = 0; j < 4; ++j)
        acc[i][j] = __builtin_amdgcn_mfma_f32_16x16x32_bf16(af[i], bfv[j],
                                                            acc[i][j], 0, 0, 0);
    __syncthreads();
  }

#pragma unroll
  for (int j = 0; j < 4; ++j) {
    const long n = n0 + wc * 64 + j * 16 + l16;
#pragma unroll
    for (int i = 0; i < 4; ++i) {
      const long mBase = m0 + wr * 64 + i * 16 + quad * 4;
#pragma unroll
      for (int r = 0; r < 4; ++r)
        C[(mBase + r) * N_out + n] = acc[i][j][r];
    }
  }
}

// ---------------------------------------------------------------------------
// NT GEMM + tanh: X1[m,n] = tanh(WE[m,:200].Wt[n,:200]^T + bt[n]), bf16 out.
// 128x128 tile, K = 6*32 + 8 tail (zero-padded).
// ---------------------------------------------------------------------------
__global__ __launch_bounds__(256, 2) void gemm_x1(
    const float* __restrict__ WE, const float* __restrict__ Wt,
    const float* __restrict__ bt, bf16_t* __restrict__ X1) {
  __shared__ __align__(16) bf16_t As[128 * 32];  // [m][k]
  __shared__ __align__(16) bf16_t Bs[128 * 32];  // [n][k]

  const int t = threadIdx.x;
  const int lane = t & 63, wave = t >> 6;
  const int wr = wave >> 1, wc = wave & 1;
  const int quad = lane >> 4, l16 = lane & 15;
  const long m0 = (long)blockIdx.y * 128;
  const long n0 = (long)blockIdx.x * 128;
  const bf16x4 z4 = {(bf16_t)0.f, (bf16_t)0.f, (bf16_t)0.f, (bf16_t)0.f};

  f32x4 acc[4][4] = {};

  for (int kt = 0; kt < 6; ++kt) {
    const int k0 = kt * 32;
#pragma unroll
    for (int r = 0; r < 4; ++r) {
      const int f = r * 256 + t;
      const int row = f >> 3, k = (f & 7) * 4;
      float4 va = *(const float4*)(WE + (m0 + row) * 200 + k0 + k);
      *(bf16x4*)&As[row * 32 + k] = cvt4(va);
      float4 vb = *(const float4*)(Wt + (n0 + row) * 200 + k0 + k);
      *(bf16x4*)&Bs[row * 32 + k] = cvt4(vb);
    }
    __syncthreads();
    bf16x8 af[4], bf[4];
#pragma unroll
    for (int i = 0; i < 4; ++i) {
      af[i] = *(const bf16x8*)&As[(wr * 64 + i * 16 + l16) * 32 + quad * 8];
      bf[i] = *(const bf16x8*)&Bs[(wc * 64 + i * 16 + l16) * 32 + quad * 8];
    }
#pragma unroll
    for (int i = 0; i < 4; ++i)
#pragma unroll
      for (int j = 0; j < 4; ++j)
        acc[i][j] = __builtin_amdgcn_mfma_f32_16x16x32_bf16(af[i], bf[j],
                                                            acc[i][j], 0, 0, 0);
    __syncthreads();
  }
  {  // k-tail: 8 valid fp32 at elem 192; pad k 8..31 with zeros
    const int row = t >> 1, half = t & 1;
    if (half == 0) {
      float4 a0 = *(const float4*)(WE + (m0 + row) * 200 + 192);
      float4 a1 = *(const float4*)(WE + (m0 + row) * 200 + 196);
      *(bf16x4*)&As[row * 32 + 0] = cvt4(a0);
      *(bf16x4*)&As[row * 32 + 4] = cvt4(a1);
      *(bf16x4*)&As[row * 32 + 8] = z4;
      *(bf16x4*)&As[row * 32 + 12] = z4;
      float4 b0 = *(const float4*)(Wt + (n0 + row) * 200 + 192);
      float4 b1 = *(const float4*)(Wt + (n0 + row) * 200 + 196);
      *(bf16x4*)&Bs[row * 32 + 0] = cvt4(b0);
      *(bf16x4*)&Bs[row * 32 + 4] = cvt4(b1);
      *(bf16x4*)&Bs[row * 32 + 8] = z4;
      *(bf16x4*)&Bs[row * 32 + 12] = z4;
    } else {
#pragma unroll
      for (int q = 4; q < 8; ++q) {
        *(bf16x4*)&As[row * 32 + q * 4] = z4;
        *(bf16x4*)&Bs[row * 32 + q * 4] = z4;
      }
    }
    __syncthreads();
    bf16x8 af[4], bf[4];
#pragma unroll
    for (int i = 0; i < 4; ++i) {
      af[i] = *(const bf16x8*)&As[(wr * 64 + i * 16 + l16) * 32 + quad * 8];
      bf[i] = *(const bf16x8*)&Bs[(wc * 64 + i * 16 + l16) * 32 + quad * 8];
    }
#pragma unroll
    for (int i = 0; i < 4; ++i)
#pragma unroll
      for (int j = 0; j < 4; ++j)
        acc[i][j] = __builtin_amdgcn_mfma_f32_16x16x32_bf16(af[i], bf[j],
                                                            acc[i][j], 0, 0, 0);
  }

  // epilogue: tanh(acc + bt[n]) -> bf16. C/D: col=lane&15, row=quad*4+reg.
#pragma unroll
  for (int j = 0; j < 4; ++j) {
    const long n = n0 + wc * 64 + j * 16 + l16;
    const float bv = bt[n];
#pragma unroll
    for (int i = 0; i < 4; ++i) {
      const long mBase = m0 + wr * 64 + i * 16 + quad * 4;
#pragma unroll
      for (int r = 0; r < 4; ++r)
        X1[(mBase + r) * 768 + n] = (bf16_t)tanhf(acc[i][j][r] + bv);
    }
  }
}

// ---------------------------------------------------------------------------
// Per (b,l): logits over W=8, softmax, Y = sum alpha*X1. In-place on RY.
// ---------------------------------------------------------------------------
__global__ __launch_bounds__(256) void attn_soft(
    const bf16_t* __restrict__ X1c,  // [bls*8, 768]
    float* __restrict__ RY) {        // [bls, 768] in: R, out: Y
  const int b = blockIdx.x;
  const int t = threadIdx.x;
  const int lane = t & 63, wave = t >> 6;
  __shared__ float red[8][4];

  float rv[3], x1[8][3];
#pragma unroll
  for (int j = 0; j < 3; ++j) {
    const int d = t + j * 256;
    rv[j] = RY[(long)b * 768 + d];
#pragma unroll
    for (int w = 0; w < 8; ++w)
      x1[w][j] = (float)X1c[((long)b * 8 + w) * 768 + d];
  }
  float part[8];
#pragma unroll
  for (int w = 0; w < 8; ++w)
    part[w] = x1[w][0] * rv[0] + x1[w][1] * rv[1] + x1[w][2] * rv[2];
#pragma unroll
  for (int o = 32; o > 0; o >>= 1)
#pragma unroll
    for (int w = 0; w < 8; ++w) part[w] += __shfl_down(part[w], o, 64);
  if (lane == 0)
#pragma unroll
    for (int w = 0; w < 8; ++w) red[w][wave] = part[w];
  __syncthreads();
  float logit[8], mx = -1e30f;
#pragma unroll
  for (int w = 0; w < 8; ++w) {
    logit[w] = red[w][0] + red[w][1] + red[w][2] + red[w][3];
    mx = fmaxf(mx, logit[w]);
  }
  float aw[8], s = 0.f;
#pragma unroll
  for (int w = 0; w < 8; ++w) {
    aw[w] = __expf(logit[w] - mx);
    s += aw[w];
  }
  const float inv = 1.f / s;
#pragma unroll
  for (int j = 0; j < 3; ++j) {
    float y = 0.f;
#pragma unroll
    for (int w = 0; w < 8; ++w) y += aw[w] * x1[w][j];
    RY[(long)b * 768 + t + j * 256] = y * inv;  // same elems this thread read
  }
}

// ---------------------------------------------------------------------------
// Final GEMM + residual + LayerNorm, in-place. 32 rows/block (256 blocks).
// out[m,n] = LN(sum_e Y[m,e] Ww[n,e] + bw[n] + LO[m,n])
// ---------------------------------------------------------------------------
__global__ __launch_bounds__(256, 2) void y_ww_ln(
    const float* __restrict__ Y, const float* __restrict__ Ww,
    const float* __restrict__ bw, const float* __restrict__ LO,
    const float* __restrict__ gamma, const float* __restrict__ beta,
    float* __restrict__ out) {
  __shared__ __align__(16) bf16_t Cbuf[32 * 768];  // 48 KiB
  __shared__ __align__(16) bf16_t As[32 * 32];     // [m][k]
  __shared__ __align__(16) bf16_t Bs[128 * 32];    // [n][k]
  __shared__ float rowpart[32][2][2];

  const int t = threadIdx.x;
  const int lane = t & 63, wave = t >> 6;
  const int wr = wave >> 1, wc = wave & 1;
  const int quad = lane >> 4, l16 = lane & 15;
  const long m0 = (long)blockIdx.x * 32;

  float s1[4] = {0.f, 0.f, 0.f, 0.f}, s2[4] = {0.f, 0.f, 0.f, 0.f};

  for (int nt = 0; nt < 6; ++nt) {
    f32x4 acc[4] = {};
    for (int kt = 0; kt < 24; ++kt) {
      const int k0 = kt * 32;
      {  // As: 32x32 = 256 float4, 1/thread
        const int row = t >> 3, k = (t & 7) * 4;
        float4 va = *(const float4*)(Y + (m0 + row) * 768 + k0 + k);
        *(bf16x4*)&As[row * 32 + k] = cvt4(va);
      }
#pragma unroll
      for (int r = 0; r < 4; ++r) {  // Bs: 128x32
        const int f = r * 256 + t;
        const int row = f >> 3, k = (f & 7) * 4;
        float4 vb = *(const float4*)(Ww + (long)(nt * 128 + row) * 768 + k0 + k);
        *(bf16x4*)&Bs[row * 32 + k] = cvt4(vb);
      }
      __syncthreads();
      const bf16x8 af = *(const bf16x8*)&As[(wr * 16 + l16) * 32 + quad * 8];
#pragma unroll
      for (int j = 0; j < 4; ++j) {
        const bf16x8 bfr =
            *(const bf16x8*)&Bs[(wc * 64 + j * 16 + l16) * 32 + quad * 8];
        acc[j] = __builtin_amdgcn_mfma_f32_16x16x32_bf16(af, bfr, acc[j], 0, 0, 0);
      }
      __syncthreads();
    }
#pragma unroll
    for (int j = 0; j < 4; ++j) {
      const int n = nt * 128 + wc * 64 + j * 16 + l16;
      const float bwv = bw[n];
#pragma unroll
      for (int r = 0; r < 4; ++r) {
        const int ml = wr * 16 + quad * 4 + r;
        const float fv = acc[j][r] + bwv + LO[(m0 + ml) * 768 + n];
        Cbuf[ml * 768 + n] = (bf16_t)fv;
        s1[r] += fv;
        s2[r] += fv * fv;
      }
    }
  }
  // reduce the 16 l16-lanes sharing each (row, wc-half)
#pragma unroll
  for (int o = 8; o > 0; o >>= 1)
#pragma unroll
    for (int r = 0; r < 4; ++r) {
      s1[r] += __shfl_down(s1[r], o, 16);
      s2[r] += __shfl_down(s2[r], o, 16);
    }
  if (l16 == 0)
#pragma unroll
    for (int r = 0; r < 4; ++r) {
      const int ml = wr * 16 + quad * 4 + r;
      rowpart[ml][wc][0] = s1[r];
      rowpart[ml][wc][1] = s2[r];
    }
  __syncthreads();

  float gv[3], bv2[3];
#pragma unroll
  for (int j = 0; j < 3; ++j) {
    gv[j] = gamma[t + j * 256];
    bv2[j] = beta[t + j * 256];
  }
  for (int r32 = 0; r32 < 32; ++r32) {
    const float S1 = rowpart[r32][0][0] + rowpart[r32][1][0];
    const float S2 = rowpart[r32][0][1] + rowpart[r32][1][1];
    const float mu = S1 * (1.f / 768.f);
    const float var = S2 * (1.f / 768.f) - mu * mu;
    const float istd = rsqrtf(var + 1e-12f);
#pragma unroll
    for (int j = 0; j < 3; ++j) {
      const int d = t + j * 256;
      const float val = ((float)Cbuf[r32 * 768 + d] - mu) * istd * gv[j] + bv2[j];
      out[(m0 + r32) * 768 + d] = val;
    }
  }
}

// ---------------------------------------------------------------------------
extern "C" void kernel_launch(void* const* d_in, const int* in_sizes, int n_in,
                              void* d_out, int out_size, void* d_ws,
                              size_t ws_size, hipStream_t stream) {
  (void)in_sizes; (void)n_in; (void)out_size;
  const float* WE = (const float*)d_in[0];   // [65536, 200]
  const float* LO = (const float*)d_in[1];   // [8192, 768]
  const float* Wt = (const float*)d_in[2];   // [768, 200]
  const float* bt = (const float*)d_in[3];   // [768]
  const float* Ww = (const float*)d_in[4];   // [768, 768]
  const float* bw = (const float*)d_in[5];   // [768]
  const float* aW = (const float*)d_in[6];   // [768, 768]
  const float* g  = (const float*)d_in[7];   // [768]
  const float* bb = (const float*)d_in[8];   // [768]
  float* out = (float*)d_out;                // [8192, 768]

  char* ws = (char*)d_ws;
  const size_t WC_BYTES = (size_t)768 * 768 * 4;  // 2,359,296
  float* Wc = (float*)ws;
  bf16_t* X1c = (bf16_t*)(ws + WC_BYTES);

  // Largest X1 chunk that fits (ws proven >= 2.36 MB in round 5).
  long Mc = 65536;
  while (Mc > 1024 && WC_BYTES + (size_t)Mc * 768 * 2 > ws_size) Mc >>= 1;
  const int S = (int)(65536 / Mc);

  const dim3 blk(256);

  // Wc = attn_W . Ww
  gemm_nn<<<dim3(6, 6), blk, 0, stream>>>(aW, Ww, Wc, 768, 768, 768, 24);
  // R = LO . Wc -> d_out
  gemm_nn<<<dim3(6, 64), blk, 0, stream>>>(LO, Wc, out, 768, 768, 768, 24);
  // chunked X1 + attention (Y overwrites R in d_out)
  for (int s = 0; s < S; ++s) {
    const long rowOff = (long)s * Mc;
    gemm_x1<<<dim3(6, Mc / 128), blk, 0, stream>>>(WE + rowOff * 200, Wt, bt, X1c);
    attn_soft<<<dim3(Mc / 8), blk, 0, stream>>>(X1c, out + (rowOff / 8) * 768);
  }
  // final GEMM + residual + LN, in-place
  y_ww_ln<<<dim3(256), blk, 0, stream>>>(out, Ww, bw, LO, g, bb, out);
}

// Round 7
// 392.343 us; speedup vs baseline: 1.4168x; 1.1331x over previous
//
#include <hip/hip_runtime.h>
#include <hip/hip_bf16.h>

// LexionAdapter — fp32 I/O, bf16-MFMA compute.
//   Wc = attn_W . Ww                      (NN)  -> ws
//   R  = LO . Wc                          (NN)  -> d_out
//   X1 = tanh(WE . Wt^T + bt)  bf16       (NT)  -> ws    [1 block = 128 rows
//        x ALL 768 cols: WE staged to LDS once, n-tile loop re-stages Wt only]
//   attn_soft: logit[w] = X1[w].R ; softmax ; Y -> d_out (elementwise over R)
//   y_ww_ln:  out = LN(Y.Ww^T + bw + LO), 32 rows/block, all-n acc in regs,
//             Y read exactly once. In-place on d_out.
// q.bw logit term is w-constant -> cancels in softmax; sum(alpha)=1.

typedef __bf16 bf16_t;
typedef bf16_t bf16x4 __attribute__((ext_vector_type(4)));
typedef bf16_t bf16x8 __attribute__((ext_vector_type(8)));
typedef float f32x4 __attribute__((ext_vector_type(4)));

__device__ __forceinline__ bf16x4 cvt4(float4 v) {
  bf16x4 o;
  o[0] = (bf16_t)v.x; o[1] = (bf16_t)v.y;
  o[2] = (bf16_t)v.z; o[3] = (bf16_t)v.w;
  return o;
}

// ---------------------------------------------------------------------------
// NN GEMM: C[M,N] = A[M,K].B[K,N], fp32, K = 32*kFull. 128x128 tile.
// (Used for Wc and R — not the bottleneck; unchanged from round 6.)
// ---------------------------------------------------------------------------
__global__ __launch_bounds__(256, 2) void gemm_nn(
    const float* __restrict__ A, const float* __restrict__ B,
    float* __restrict__ C, int ldA, int ldB, int N_out, int kFull) {
  __shared__ __align__(16) bf16_t As[128 * 32];  // [m][k]
  __shared__ __align__(16) bf16_t Bs[32 * 128];  // [k][n]

  const int t = threadIdx.x;
  const int lane = t & 63, wave = t >> 6;
  const int wr = wave >> 1, wc = wave & 1;
  const int quad = lane >> 4, l16 = lane & 15;
  const long m0 = (long)blockIdx.y * 128;
  const long n0 = (long)blockIdx.x * 128;

  f32x4 acc[4][4] = {};

  for (int kt = 0; kt < kFull; ++kt) {
    const int k0 = kt * 32;
#pragma unroll
    for (int r = 0; r < 4; ++r) {
      const int f = r * 256 + t;
      const int arow = f >> 3, ak = (f & 7) * 4;
      float4 va = *(const float4*)(A + (m0 + arow) * ldA + k0 + ak);
      *(bf16x4*)&As[arow * 32 + ak] = cvt4(va);
      const int brow = f >> 5, bc = (f & 31) * 4;
      float4 vb = *(const float4*)(B + (long)(k0 + brow) * ldB + n0 + bc);
      *(bf16x4*)&Bs[brow * 128 + bc] = cvt4(vb);
    }
    __syncthreads();

    bf16x8 af[4], bfv[4];
#pragma unroll
    for (int i = 0; i < 4; ++i)
      af[i] = *(const bf16x8*)&As[(wr * 64 + i * 16 + l16) * 32 + quad * 8];
#pragma unroll
    for (int j = 0; j < 4; ++j) {
      const int n = wc * 64 + j * 16 + l16;
#pragma unroll
      for (int jj = 0; jj < 8; ++jj)
        bfv[j][jj] = Bs[(quad * 8 + jj) * 128 + n];
    }
#pragma unroll
    for (int i = 0; i < 4; ++i)
#pragma unroll
      for (int j = 0; j < 4; ++j)
        acc[i][j] = __builtin_amdgcn_mfma_f32_16x16x32_bf16(af[i], bfv[j],
                                                            acc[i][j], 0, 0, 0);
    __syncthreads();
  }

#pragma unroll
  for (int j = 0; j < 4; ++j) {
    const long n = n0 + wc * 64 + j * 16 + l16;
#pragma unroll
    for (int i = 0; i < 4; ++i) {
      const long mBase = m0 + wr * 64 + i * 16 + quad * 4;
#pragma unroll
      for (int r = 0; r < 4; ++r)
        C[(mBase + r) * N_out + n] = acc[i][j][r];
    }
  }
}

// ---------------------------------------------------------------------------
// X1 = tanh(WE . Wt^T + bt), bf16 out. One block = 128 rows x ALL 768 cols.
// WE tile staged ONCE (128 x 224 bf16, k 200..223 zero); n-loop re-stages Wt.
// LDS strides padded (232 / 40 elems) -> 2-way (free) bank pattern.
// ---------------------------------------------------------------------------
#define AS_LD 232
#define BS_LD 40
__global__ __launch_bounds__(256, 2) void gemm_x1(
    const float* __restrict__ WE, const float* __restrict__ Wt,
    const float* __restrict__ bt, bf16_t* __restrict__ X1) {
  __shared__ __align__(16) bf16_t As[128 * AS_LD];  // 58 KiB
  __shared__ __align__(16) bf16_t Bs[128 * BS_LD];  // 10 KiB

  const int t = threadIdx.x;
  const int lane = t & 63, wave = t >> 6;
  const int wr = wave >> 1, wc = wave & 1;
  const int quad = lane >> 4, l16 = lane & 15;
  const long m0 = (long)blockIdx.x * 128;
  const bf16x4 z4 = {(bf16_t)0.f, (bf16_t)0.f, (bf16_t)0.f, (bf16_t)0.f};

  // ---- Stage full WE tile once. Global addr = WE + m0*200 + 4*f (contig). ----
  const float* WEb = WE + m0 * 200;
#pragma unroll
  for (int r = 0; r < 25; ++r) {  // 6400 float4 = 128 rows x 50
    const int f = r * 256 + t;
    const int row = f / 50, idx = f - row * 50;
    float4 va = *(const float4*)(WEb + 4 * f);
    *(bf16x4*)&As[row * AS_LD + idx * 4] = cvt4(va);
  }
#pragma unroll
  for (int r = 0; r < 4; ++r) {  // zero k = 200..231 (1024 bf16x4 slots)
    const int s = r * 256 + t;
    const int row = s >> 3, q = s & 7;
    *(bf16x4*)&As[row * AS_LD + 200 + q * 4] = z4;
  }
  __syncthreads();

  // ---- n-tile loop ----
  for (int nt = 0; nt < 6; ++nt) {
    const long n0 = (long)nt * 128;
    f32x4 acc[4][4] = {};
    for (int kt = 0; kt < 7; ++kt) {
      // stage Wt tile [128 x 32] (kt=6: 8 valid + zeros)
#pragma unroll
      for (int r = 0; r < 4; ++r) {
        const int f = r * 256 + t;
        const int row = f >> 3, k4 = (f & 7) * 4;
        const int k = kt * 32 + k4;
        if (k < 200) {
          float4 vb = *(const float4*)(Wt + (n0 + row) * 200 + k);
          *(bf16x4*)&Bs[row * BS_LD + k4] = cvt4(vb);
        } else {
          *(bf16x4*)&Bs[row * BS_LD + k4] = z4;
        }
      }
      __syncthreads();
      bf16x8 af[4], bf[4];
#pragma unroll
      for (int i = 0; i < 4; ++i) {
        af[i] = *(const bf16x8*)&As[(wr * 64 + i * 16 + l16) * AS_LD +
                                    kt * 32 + quad * 8];
        bf[i] = *(const bf16x8*)&Bs[(wc * 64 + i * 16 + l16) * BS_LD + quad * 8];
      }
#pragma unroll
      for (int i = 0; i < 4; ++i)
#pragma unroll
        for (int j = 0; j < 4; ++j)
          acc[i][j] = __builtin_amdgcn_mfma_f32_16x16x32_bf16(af[i], bf[j],
                                                              acc[i][j], 0, 0, 0);
      __syncthreads();
    }
    // epilogue: tanh(acc + bt[n]) -> bf16. C/D: col=lane&15, row=quad*4+reg.
#pragma unroll
    for (int j = 0; j < 4; ++j) {
      const long n = n0 + wc * 64 + j * 16 + l16;
      const float bv = bt[n];
#pragma unroll
      for (int i = 0; i < 4; ++i) {
        const long mBase = m0 + wr * 64 + i * 16 + quad * 4;
#pragma unroll
        for (int r = 0; r < 4; ++r)
          X1[(mBase + r) * 768 + n] = (bf16_t)tanhf(acc[i][j][r] + bv);
      }
    }
  }
}

// ---------------------------------------------------------------------------
// Per (b,l): logits over W=8, softmax, Y = sum alpha*X1. In-place on RY.
// ---------------------------------------------------------------------------
__global__ __launch_bounds__(256) void attn_soft(
    const bf16_t* __restrict__ X1c,  // [bls*8, 768]
    float* __restrict__ RY) {        // [bls, 768] in: R, out: Y
  const int b = blockIdx.x;
  const int t = threadIdx.x;
  const int lane = t & 63, wave = t >> 6;
  __shared__ float red[8][4];

  float rv[3], x1[8][3];
#pragma unroll
  for (int j = 0; j < 3; ++j) {
    const int d = t + j * 256;
    rv[j] = RY[(long)b * 768 + d];
#pragma unroll
    for (int w = 0; w < 8; ++w)
      x1[w][j] = (float)X1c[((long)b * 8 + w) * 768 + d];
  }
  float part[8];
#pragma unroll
  for (int w = 0; w < 8; ++w)
    part[w] = x1[w][0] * rv[0] + x1[w][1] * rv[1] + x1[w][2] * rv[2];
#pragma unroll
  for (int o = 32; o > 0; o >>= 1)
#pragma unroll
    for (int w = 0; w < 8; ++w) part[w] += __shfl_down(part[w], o, 64);
  if (lane == 0)
#pragma unroll
    for (int w = 0; w < 8; ++w) red[w][wave] = part[w];
  __syncthreads();
  float logit[8], mx = -1e30f;
#pragma unroll
  for (int w = 0; w < 8; ++w) {
    logit[w] = red[w][0] + red[w][1] + red[w][2] + red[w][3];
    mx = fmaxf(mx, logit[w]);
  }
  float aw[8], s = 0.f;
#pragma unroll
  for (int w = 0; w < 8; ++w) {
    aw[w] = __expf(logit[w] - mx);
    s += aw[w];
  }
  const float inv = 1.f / s;
#pragma unroll
  for (int j = 0; j < 3; ++j) {
    float y = 0.f;
#pragma unroll
    for (int w = 0; w < 8; ++w) y += aw[w] * x1[w][j];
    RY[(long)b * 768 + t + j * 256] = y * inv;
  }
}

// ---------------------------------------------------------------------------
// out = LN(Y.Ww^T + bw + LO), in-place. One block = 32 rows x ALL 768 cols.
// Y read once; acc for all 6 n-tiles in registers; wave wc owns 192-col slab.
// ---------------------------------------------------------------------------
__global__ __launch_bounds__(256, 2) void y_ww_ln(
    const float* __restrict__ Y, const float* __restrict__ Ww,
    const float* __restrict__ bw, const float* __restrict__ LO,
    const float* __restrict__ gamma, const float* __restrict__ beta,
    float* __restrict__ out) {
  __shared__ __align__(16) bf16_t Ys[32 * BS_LD];   // 2.5 KiB [m][k]
  __shared__ __align__(16) bf16_t Bs[768 * BS_LD];  // 60 KiB  [n][k]
  __shared__ float rowstats[32][4][2];

  const int t = threadIdx.x;
  const int lane = t & 63, wc = t >> 6;  // wave wc in 0..3: n-slab wc*192
  const int quad = lane >> 4, l16 = lane & 15;
  const long m0 = (long)blockIdx.x * 32;

  f32x4 acc[2][12] = {};

  for (int kt = 0; kt < 24; ++kt) {
    const int k0 = kt * 32;
    {  // Ys: 32x32 = 256 float4, 1/thread
      const int row = t >> 3, k4 = (t & 7) * 4;
      float4 va = *(const float4*)(Y + (m0 + row) * 768 + k0 + k4);
      *(bf16x4*)&Ys[row * BS_LD + k4] = cvt4(va);
    }
#pragma unroll
    for (int r = 0; r < 24; ++r) {  // Bs: 768x32 = 6144 float4
      const int f = r * 256 + t;
      const int row = f >> 3, k4 = (f & 7) * 4;
      float4 vb = *(const float4*)(Ww + (long)row * 768 + k0 + k4);
      *(bf16x4*)&Bs[row * BS_LD + k4] = cvt4(vb);
    }
    __syncthreads();
    bf16x8 af[2], bf[12];
#pragma unroll
    for (int i = 0; i < 2; ++i)
      af[i] = *(const bf16x8*)&Ys[(i * 16 + l16) * BS_LD + quad * 8];
#pragma unroll
    for (int j = 0; j < 12; ++j)
      bf[j] = *(const bf16x8*)&Bs[(wc * 192 + j * 16 + l16) * BS_LD + quad * 8];
#pragma unroll
    for (int i = 0; i < 2; ++i)
#pragma unroll
      for (int j = 0; j < 12; ++j)
        acc[i][j] = __builtin_amdgcn_mfma_f32_16x16x32_bf16(af[i], bf[j],
                                                            acc[i][j], 0, 0, 0);
    __syncthreads();
  }

  // epilogue: fv = acc + bw + LO; row stats; LN; store fp32.
  float s1[2][4] = {}, s2[2][4] = {};
#pragma unroll
  for (int i = 0; i < 2; ++i)
#pragma unroll
    for (int j = 0; j < 12; ++j) {
      const int n = wc * 192 + j * 16 + l16;
      const float bwv = bw[n];
#pragma unroll
      for (int r = 0; r < 4; ++r) {
        const int ml = i * 16 + quad * 4 + r;
        const float fv = acc[i][j][r] + bwv + LO[(m0 + ml) * 768 + n];
        acc[i][j][r] = fv;
        s1[i][r] += fv;
        s2[i][r] += fv * fv;
      }
    }
#pragma unroll
  for (int o = 8; o > 0; o >>= 1)
#pragma unroll
    for (int i = 0; i < 2; ++i)
#pragma unroll
      for (int r = 0; r < 4; ++r) {
        s1[i][r] += __shfl_down(s1[i][r], o, 16);
        s2[i][r] += __shfl_down(s2[i][r], o, 16);
      }
  if (l16 == 0)
#pragma unroll
    for (int i = 0; i < 2; ++i)
#pragma unroll
      for (int r = 0; r < 4; ++r) {
        const int ml = i * 16 + quad * 4 + r;
        rowstats[ml][wc][0] = s1[i][r];
        rowstats[ml][wc][1] = s2[i][r];
      }
  __syncthreads();

#pragma unroll
  for (int i = 0; i < 2; ++i) {
    float mu[4], istd[4];
#pragma unroll
    for (int r = 0; r < 4; ++r) {
      const int ml = i * 16 + quad * 4 + r;
      const float S1 = rowstats[ml][0][0] + rowstats[ml][1][0] +
                       rowstats[ml][2][0] + rowstats[ml][3][0];
      const float S2 = rowstats[ml][0][1] + rowstats[ml][1][1] +
                       rowstats[ml][2][1] + rowstats[ml][3][1];
      mu[r] = S1 * (1.f / 768.f);
      const float var = S2 * (1.f / 768.f) - mu[r] * mu[r];
      istd[r] = rsqrtf(var + 1e-12f);
    }
#pragma unroll
    for (int j = 0; j < 12; ++j) {
      const int n = wc * 192 + j * 16 + l16;
      const float gv = gamma[n], bv = beta[n];
#pragma unroll
      for (int r = 0; r < 4; ++r) {
        const int ml = i * 16 + quad * 4 + r;
        out[(m0 + ml) * 768 + n] = (acc[i][j][r] - mu[r]) * istd[r] * gv + bv;
      }
    }
  }
}

// ---------------------------------------------------------------------------
extern "C" void kernel_launch(void* const* d_in, const int* in_sizes, int n_in,
                              void* d_out, int out_size, void* d_ws,
                              size_t ws_size, hipStream_t stream) {
  (void)in_sizes; (void)n_in; (void)out_size;
  const float* WE = (const float*)d_in[0];   // [65536, 200]
  const float* LO = (const float*)d_in[1];   // [8192, 768]
  const float* Wt = (const float*)d_in[2];   // [768, 200]
  const float* bt = (const float*)d_in[3];   // [768]
  const float* Ww = (const float*)d_in[4];   // [768, 768]
  const float* bw = (const float*)d_in[5];   // [768]
  const float* aW = (const float*)d_in[6];   // [768, 768]
  const float* g  = (const float*)d_in[7];   // [768]
  const float* bb = (const float*)d_in[8];   // [768]
  float* out = (float*)d_out;                // [8192, 768]

  char* ws = (char*)d_ws;
  const size_t WC_BYTES = (size_t)768 * 768 * 4;
  float* Wc = (float*)ws;
  bf16_t* X1c = (bf16_t*)(ws + WC_BYTES);

  long Mc = 65536;
  while (Mc > 1024 && WC_BYTES + (size_t)Mc * 768 * 2 > ws_size) Mc >>= 1;
  const int S = (int)(65536 / Mc);

  const dim3 blk(256);

  // Wc = attn_W . Ww
  gemm_nn<<<dim3(6, 6), blk, 0, stream>>>(aW, Ww, Wc, 768, 768, 768, 24);
  // R = LO . Wc -> d_out
  gemm_nn<<<dim3(6, 64), blk, 0, stream>>>(LO, Wc, out, 768, 768, 768, 24);
  // chunked X1 + attention (Y overwrites R in d_out)
  for (int s = 0; s < S; ++s) {
    const long rowOff = (long)s * Mc;
    gemm_x1<<<dim3(Mc / 128), blk, 0, stream>>>(WE + rowOff * 200, Wt, bt, X1c);
    attn_soft<<<dim3(Mc / 8), blk, 0, stream>>>(X1c, out + (rowOff / 8) * 768);
  }
  // final GEMM + residual + LN, in-place
  y_ww_ln<<<dim3(256), blk, 0, stream>>>(out, Ww, bw, LO, g, bb, out);
}